// Round 2
// baseline (323.190 us; speedup 1.0000x reference)
//
#include <hip/hip_runtime.h>

#define LT_N 8192

// Lower-triangular matvec, y[i] = sum_{j<=i} W[i,j]*x[j].
// One wave handles the row PAIR (w, 8191-w): combined length = 8193 for every
// wave -> perfectly uniform work across all 4096 waves. 1024 blocks x 256thr
// = 4 blocks/CU (32 KiB LDS each, 128/160 KiB) -> whole grid co-resident,
// no scheduling tail. Fused loop streams both rows against shared xs for
// 2-3 independent global_load_dwordx4 in flight per wave.
__global__ __launch_bounds__(256, 4) void tril_matvec_kernel(
    const float* __restrict__ x,
    const float* __restrict__ W,
    float* __restrict__ y)
{
    __shared__ float xs[LT_N];

    // Stage x into LDS: 8192 floats / (256 thr * 4/float4) = 8 iters.
    {
        const float4* x4 = (const float4*)x;
        float4* xs4 = (float4*)xs;
        #pragma unroll
        for (int i = 0; i < 8; ++i)
            xs4[threadIdx.x + i * 256] = x4[threadIdx.x + i * 256];
    }
    __syncthreads();

    const int wave = threadIdx.x >> 6;
    const int lane = threadIdx.x & 63;
    const int w = blockIdx.x * 4 + wave;      // 0..4095
    const int rA = w;                         // short row, len 1..4096
    const int rB = LT_N - 1 - w;              // long row,  len 4097..8192

    const float* WrA = W + (size_t)rA * LT_N;
    const float* WrB = W + (size_t)rB * LT_N;
    const int lenA  = rA + 1;
    const int lenB  = rB + 1;
    const int lenA4 = lenA & ~3;
    const int lenB4 = lenB & ~3;

    float accA = 0.f, accB0 = 0.f, accB1 = 0.f;

    int j = lane * 4;   // lane-private column cursor; wave covers 256 floats/step

    // Fused prefix: both rows active (j < lenA4 <= lenB4). Two independent
    // global streams + one LDS stream per iteration.
    for (; j < lenA4; j += 256) {
        float4 a  = *(const float4*)(WrA + j);
        float4 b  = *(const float4*)(WrB + j);
        float4 xv = *(const float4*)(xs + j);
        accA  += a.x * xv.x + a.y * xv.y + a.z * xv.z + a.w * xv.w;
        accB0 += b.x * xv.x + b.y * xv.y + b.z * xv.z + b.w * xv.w;
    }
    // Long-row remainder, unrolled x2 (two independent 16B loads in flight).
    for (; j + 256 < lenB4; j += 512) {
        float4 b0 = *(const float4*)(WrB + j);
        float4 b1 = *(const float4*)(WrB + j + 256);
        float4 x0 = *(const float4*)(xs + j);
        float4 x1 = *(const float4*)(xs + j + 256);
        accB0 += b0.x * x0.x + b0.y * x0.y + b0.z * x0.z + b0.w * x0.w;
        accB1 += b1.x * x1.x + b1.y * x1.y + b1.z * x1.z + b1.w * x1.w;
    }
    for (; j < lenB4; j += 256) {
        float4 b0 = *(const float4*)(WrB + j);
        float4 x0 = *(const float4*)(xs + j);
        accB0 += b0.x * x0.x + b0.y * x0.y + b0.z * x0.z + b0.w * x0.w;
    }

    // Scalar tails (<=3 elements each).
    const int remA = lenA - lenA4;
    if (lane < remA) accA  += WrA[lenA4 + lane] * xs[lenA4 + lane];
    const int remB = lenB - lenB4;
    if (lane < remB) accB0 += WrB[lenB4 + lane] * xs[lenB4 + lane];

    float accB = accB0 + accB1;

    // Wave64 tree reduction for both rows.
    #pragma unroll
    for (int off = 32; off > 0; off >>= 1) {
        accA += __shfl_down(accA, off, 64);
        accB += __shfl_down(accB, off, 64);
    }

    if (lane == 0) {
        y[rA] = accA;
        y[rB] = accB;
    }
}

extern "C" void kernel_launch(void* const* d_in, const int* in_sizes, int n_in,
                              void* d_out, int out_size, void* d_ws, size_t ws_size,
                              hipStream_t stream)
{
    const float* x = (const float*)d_in[0];
    const float* W = (const float*)d_in[1];
    float* y = (float*)d_out;

    // 4096 row-pairs, 4 waves per 256-thread block -> 1024 blocks (4/CU).
    dim3 grid(1024);
    dim3 block(256);
    tril_matvec_kernel<<<grid, block, 0, stream>>>(x, W, y);
}